// Round 6
// baseline (532.489 us; speedup 1.0000x reference)
//
#include <hip/hip_runtime.h>
#include <math.h>

#define NB 2
#define NPTS 8192
#define CH 128
#define KNN 16
#define K17 17
#define EPSI 1e-5f
#define SLOPE 0.2f
#define NCH 32        // filter chunks
#define CHSZ 256      // candidates per chunk
#define SCAP 16       // survivor cap per chunk
#define BIGF 3.0e38f

// ---------------- workspace layout (bytes) ----------------
// idx  [B][N][16] int            @ 0            (1 MB)
// x0b  [B][N][128] f32           @ 1,048,576    (8 MB)   } surv aliases
// ym1  [B][N][128] f32           @ 9,437,184    (8 MB)
// ym2  [B][N][256] f32           @ 17,825,792   (16 MB)
// uv   [B][N][512] f32           @ 34,603,008   (32 MB)
// y4   [B][N][128] f32           @ 68,157,440   (8 MB)   } pa aliases y4
// counts [B][N][32] int          @ 76,546,048   (2 MB)
// tau                            @ 78,643,200   (64 KB)
// Wm1t [128k][256m]              @ 78,708,736   (128 KB)
// Wm2t [128k][512m]              @ 78,839,808   (256 KB)
// stats (2048 f32)               @ 79,101,952
// scb1 [B][128] float2           @ 79,110,144
// scb2 [B][256] float2           @ 79,112,192
// pts4 [B][N] float4             @ 79,116,288   (256 KB)
// W3t  [512k][128m]              @ 79,378,432   (256 KB)
#define OFF_IDX   0L
#define OFF_X0B   1048576L
#define OFF_YM1   9437184L
#define OFF_YM2   17825792L
#define OFF_UV    34603008L
#define OFF_Y4    68157440L
#define OFF_SURV  OFF_X0B
#define OFF_PA    OFF_Y4
#define OFF_CNT   76546048L
#define OFF_TAU   78643200L
#define OFF_WM1T  78708736L
#define OFF_WM2T  78839808L
#define OFF_STATS 79101952L
#define OFF_SCB1  79110144L
#define OFF_SCB2  79112192L
#define OFF_PTS4  79116288L
#define OFF_W3T   79378432L

// ---------------- small utility kernels ----------------

__global__ void zero_stats_k(float* __restrict__ stats) {
  int t = blockIdx.x * 256 + threadIdx.x;
  if (t < 2048) stats[t] = 0.f;
}

// features [B][128][N] -> x0b[b][n][0:128]
__global__ void transpose_x0_k(const float* __restrict__ feat, float* __restrict__ x0b) {
  __shared__ float tile[32][33];
  int b = blockIdx.z;
  int n0 = blockIdx.x * 32, c0 = blockIdx.y * 32;
  int tx = threadIdx.x;
  for (int ty = threadIdx.y; ty < 32; ty += 8)
    tile[ty][tx] = feat[((long)b * CH + c0 + ty) * NPTS + n0 + tx];
  __syncthreads();
  for (int ty = threadIdx.y; ty < 32; ty += 8)
    x0b[((long)b * NPTS + n0 + ty) * 128 + c0 + tx] = tile[tx][ty];
}

// Transposed weight prep: Wm1t[k][m] (k<128,m<256), Wm2t[k][m] (k<128,m<512),
// W3t[k][m] (k<512,m<128). Edge-decomposition folded in for W1/W2:
//   m < Cout_half: center-coeff minus neighbor-coeff; else neighbor-coeff.
__global__ void prep_wt_k(const float* __restrict__ W1, const float* __restrict__ W2,
                          const float* __restrict__ W3, float* __restrict__ Wm1t,
                          float* __restrict__ Wm2t, float* __restrict__ W3t) {
  int t = blockIdx.x * 256 + threadIdx.x;
  if (t < 32768) {                       // Wm1t: t = k*256 + m
    int k = t >> 8, m = t & 255;
    Wm1t[t] = (m < 128) ? (W1[m * 256 + k] - W1[m * 256 + 128 + k])
                        : W1[(m - 128) * 256 + 128 + k];
  } else if (t < 98304) {                // Wm2t: idx = k*512 + m
    int idx = t - 32768;
    int k = idx >> 9, m = idx & 511;
    Wm2t[idx] = (m < 256) ? (W2[m * 256 + k] - W2[m * 256 + 128 + k])
                          : W2[(m - 256) * 256 + 128 + k];
  } else if (t < 163840) {               // W3t: idx = k*128 + m
    int idx = t - 98304;
    int k = idx >> 7, m = idx & 127;
    W3t[idx] = W3[m * 512 + k];
  }
}

// sums (sum, sumsq) -> (scale, bias) per (b, col):  z = y*scale + bias
__global__ void finalize_scb_k(const float* __restrict__ stats, float2* __restrict__ scb,
                               int count, float cinv) {
  int t = blockIdx.x * 256 + threadIdx.x;
  if (t < count) {
    float mean = stats[t * 2] * cinv;
    float var = stats[t * 2 + 1] * cinv - mean * mean;
    float inv = rsqrtf(var + EPSI);
    scb[t] = make_float2(inv, -mean * inv);
  }
}

// ---------------- KNN ----------------
__global__ void knn_prep_k(const float* __restrict__ coords, float4* __restrict__ pts) {
  int b = blockIdx.y;
  int i = blockIdx.x * 256 + threadIdx.x;
  const float* cb = coords + (long)b * 3 * NPTS;
  float x = cb[i], y = cb[NPTS + i], z = cb[2 * NPTS + i];
  float sq = __fadd_rn(__fadd_rn(__fmul_rn(x, x), __fmul_rn(y, y)), __fmul_rn(z, z));
  pts[(long)b * NPTS + i] = make_float4(x, y, z, sq);
}

#define DIST(pi, pj, d2)                                                          \
  float dot = __fadd_rn(__fadd_rn(__fmul_rn((pi).x, (pj).x), __fmul_rn((pi).y, (pj).y)), \
                        __fmul_rn((pi).z, (pj).z));                               \
  float d2 = __fsub_rn(__fadd_rn((pi).w, (pj).w), __fmul_rn(2.0f, dot));

// Stable predicated insertion into ascending (d, id) list; ties keep earlier insert.
#define KNN_INSERT(d2v, jv)                                              \
  if ((d2v) < d[K17 - 1]) {                                              \
    _Pragma("unroll")                                                    \
    for (int s = K17 - 1; s > 0; --s) {                                  \
      if ((d2v) < d[s - 1]) { d[s] = d[s - 1]; id[s] = id[s - 1]; }      \
      else if ((d2v) < d[s]) { d[s] = (d2v); id[s] = (jv); }             \
    }                                                                    \
    if ((d2v) < d[0]) { d[0] = (d2v); id[0] = (jv); }                    \
  }

// Phase A: 32 sub-threads per point; sub s keeps top-2 of sample candidates
// j in [s*64, s*64+64) (sample = first 2048 points).
__global__ __launch_bounds__(256) void knn_phaseA_k(const float4* __restrict__ pts,
                                                    float2* __restrict__ pa) {
  int b = blockIdx.y;
  int ib = blockIdx.x & 127;
  int sg = blockIdx.x >> 7;          // 0..7
  int i = ib * 64 + (threadIdx.x & 63);
  int sub = sg * 4 + (threadIdx.x >> 6);   // 0..31
  const float4* P = pts + (long)b * NPTS;
  float4 pi = P[i];
  float d0 = BIGF, d1 = BIGF;
  int i0 = 0x7fffffff, i1 = 0x7fffffff;
  int j0 = sub * 64;
  for (int jj = 0; jj < 64; ++jj) {
    float4 pj = P[j0 + jj];
    DIST(pi, pj, d2)
    if (d2 < d1) {
      if (d2 < d0) { d1 = d0; i1 = i0; d0 = d2; i0 = j0 + jj; }
      else { d1 = d2; i1 = j0 + jj; }
    }
  }
  long base = (((long)b * NPTS + i) * 32 + sub) * 2;
  pa[base] = make_float2(d0, __int_as_float(i0));
  pa[base + 1] = make_float2(d1, __int_as_float(i1));
}

// Merge 32x2 partials -> tau = 17th smallest of the 64 sample distances
__global__ __launch_bounds__(256) void knn_mergeA_k(const float2* __restrict__ pa,
                                                    float* __restrict__ tau) {
  int b = blockIdx.y;
  int i = blockIdx.x * 256 + threadIdx.x;
  float d[K17]; int id[K17];
#pragma unroll
  for (int s = 0; s < K17; ++s) { d[s] = BIGF; id[s] = 0x7fffffff; }
  long base = ((long)b * NPTS + i) * 64;
  for (int c = 0; c < 64; ++c) {
    float2 v = pa[base + c];
    if (v.x < d[K17 - 1]) {
      int j = __float_as_int(v.y);
      KNN_INSERT(v.x, j);
    }
  }
  tau[(long)b * NPTS + i] = d[K17 - 1];
}

// Phase B: per (i, chunk) thread, append all candidates with d2 <= tau_i.
__global__ __launch_bounds__(256) void knn_filter_k(const float4* __restrict__ pts,
                                                    const float* __restrict__ tau,
                                                    float2* __restrict__ surv,
                                                    int* __restrict__ counts) {
  int b = blockIdx.z;
  int i = blockIdx.x * 256 + threadIdx.x;
  int chunk = blockIdx.y;
  const float4* P = pts + (long)b * NPTS;
  float4 pi = P[i];
  float t = tau[(long)b * NPTS + i];
  long sbase = (((long)b * NPTS + i) * NCH + chunk) * SCAP;
  int cnt = 0;
  int j0 = chunk * CHSZ;
#pragma unroll 2
  for (int jj = 0; jj < CHSZ; ++jj) {
    float4 pj = P[j0 + jj];
    DIST(pi, pj, d2)
    if (d2 <= t) {
      if (cnt < SCAP) surv[sbase + cnt] = make_float2(d2, __int_as_float(j0 + jj));
      cnt++;
    }
  }
  counts[((long)b * NPTS + i) * NCH + chunk] = cnt;
}

// Fused Merge-B: block = 32 points x 8 subs, each sub merges 4 chunks into a
// register top-17, 3-level LDS insert-merge tree.
__global__ __launch_bounds__(256) void knn_mergeB_k(const float2* __restrict__ surv,
                                                    const int* __restrict__ counts,
                                                    const float4* __restrict__ pts,
                                                    int* __restrict__ idxo) {
  __shared__ float2 lds[8][K17][32];
  int b = blockIdx.y;
  int pl = threadIdx.x & 31;
  int sub = threadIdx.x >> 5;
  int i = blockIdx.x * 32 + pl;
  const float4* P = pts + (long)b * NPTS;
  float4 pi = P[i];
  float d[K17]; int id[K17];
#pragma unroll
  for (int s = 0; s < K17; ++s) { d[s] = BIGF; id[s] = 0x7fffffff; }
  long cbase = ((long)b * NPTS + i) * NCH;
  int4 c4 = *(const int4*)(counts + cbase + sub * 4);
  int cnt4[4] = {c4.x, c4.y, c4.z, c4.w};
#pragma unroll
  for (int q = 0; q < 4; ++q) {
    int c = sub * 4 + q;
    int cnt = cnt4[q];
    if (cnt > SCAP) {
      int j0 = c * CHSZ;
      for (int jj = 0; jj < CHSZ; ++jj) {
        float4 pj = P[j0 + jj];
        DIST(pi, pj, d2)
        KNN_INSERT(d2, j0 + jj);
      }
    } else {
      long sb = (cbase + c) * SCAP;
      for (int p = 0; p < cnt; p += 2) {
        float4 v2 = *(const float4*)(surv + sb + p);
        if (v2.x < d[K17 - 1]) {
          int j = __float_as_int(v2.y);
          KNN_INSERT(v2.x, j);
        }
        if (p + 1 < cnt && v2.z < d[K17 - 1]) {
          int j = __float_as_int(v2.w);
          KNN_INSERT(v2.z, j);
        }
      }
    }
  }
#pragma unroll
  for (int s = 0; s < K17; ++s) lds[sub][s][pl] = make_float2(d[s], __int_as_float(id[s]));
  __syncthreads();
  if ((sub & 1) == 0) {
#pragma unroll
    for (int s = 0; s < K17; ++s) {
      float2 v = lds[sub + 1][s][pl];
      if (v.x < d[K17 - 1]) {
        int j = __float_as_int(v.y);
        KNN_INSERT(v.x, j);
      }
    }
  }
  __syncthreads();
  if ((sub & 1) == 0) {
#pragma unroll
    for (int s = 0; s < K17; ++s) lds[sub >> 1][s][pl] = make_float2(d[s], __int_as_float(id[s]));
  }
  __syncthreads();
  if (sub < 2) {
#pragma unroll
    for (int s = 0; s < K17; ++s) {
      float2 v = lds[2 * sub][s][pl];
      d[s] = v.x; id[s] = __float_as_int(v.y);
    }
#pragma unroll
    for (int s = 0; s < K17; ++s) {
      float2 v = lds[2 * sub + 1][s][pl];
      if (v.x < d[K17 - 1]) {
        int j = __float_as_int(v.y);
        KNN_INSERT(v.x, j);
      }
    }
  }
  __syncthreads();
  if (sub < 2) {
#pragma unroll
    for (int s = 0; s < K17; ++s) lds[sub][s][pl] = make_float2(d[s], __int_as_float(id[s]));
  }
  __syncthreads();
  if (sub == 0) {
#pragma unroll
    for (int s = 0; s < K17; ++s) {
      float2 v = lds[0][s][pl];
      d[s] = v.x; id[s] = __float_as_int(v.y);
    }
#pragma unroll
    for (int s = 0; s < K17; ++s) {
      float2 v = lds[1][s][pl];
      if (v.x < d[K17 - 1]) {
        int j = __float_as_int(v.y);
        KNN_INSERT(v.x, j);
      }
    }
    long ob = ((long)b * NPTS + i) * KNN;
#pragma unroll
    for (int s = 1; s < K17; ++s) idxo[ob + s - 1] = id[s];
  }
}

#define AFFLK4(v, a0, a1, a2, a3)                              \
  v.x = fmaf(v.x, a0.x, a0.y); v.x = fmaxf(v.x, SLOPE * v.x);  \
  v.y = fmaf(v.y, a1.x, a1.y); v.y = fmaxf(v.y, SLOPE * v.y);  \
  v.z = fmaf(v.z, a2.x, a2.y); v.z = fmaxf(v.z, SLOPE * v.z);  \
  v.w = fmaf(v.w, a3.x, a3.y); v.w = fmaxf(v.w, SLOPE * v.w);

// 4 consecutive k-steps: xv holds X[row][k0..k0+3]; wr -> Wt[k0][m0..m0+15].
// Wt address is wave-uniform -> scalar (SMEM) loads, no VALU/LDS cost.
__device__ __forceinline__ void mac4(float acc[16], float4 xv, const float* __restrict__ wr,
                                     int M) {
  float xk[4] = {xv.x, xv.y, xv.z, xv.w};
#pragma unroll
  for (int c = 0; c < 4; ++c) {
    const float4 w0 = *(const float4*)(wr);
    const float4 w1 = *(const float4*)(wr + 4);
    const float4 w2 = *(const float4*)(wr + 8);
    const float4 w3 = *(const float4*)(wr + 12);
    float x = xk[c];
    acc[0] = fmaf(x, w0.x, acc[0]);   acc[1] = fmaf(x, w0.y, acc[1]);
    acc[2] = fmaf(x, w0.z, acc[2]);   acc[3] = fmaf(x, w0.w, acc[3]);
    acc[4] = fmaf(x, w1.x, acc[4]);   acc[5] = fmaf(x, w1.y, acc[5]);
    acc[6] = fmaf(x, w1.z, acc[6]);   acc[7] = fmaf(x, w1.w, acc[7]);
    acc[8] = fmaf(x, w2.x, acc[8]);   acc[9] = fmaf(x, w2.y, acc[9]);
    acc[10] = fmaf(x, w2.z, acc[10]); acc[11] = fmaf(x, w2.w, acc[11]);
    acc[12] = fmaf(x, w3.x, acc[12]); acc[13] = fmaf(x, w3.y, acc[13]);
    acc[14] = fmaf(x, w3.z, acc[14]); acc[15] = fmaf(x, w3.w, acc[15]);
    wr += M;
  }
}

// ---------------- row-dot GEMM (round 6): Out[b][n][m] = sum_k X[b][n][k]*Wt[k][m]
// Thread = one n-row x 16 m-cols (acc[16]). NO LDS, NO barriers:
//  - X streamed from global, each thread reads its OWN contiguous row
//    (8 consecutive dwordx4 per 32-k window -> L1-resident, sequential).
//  - W transposed [K][M]; per-kk row address depends only on blockIdx/loop
//    -> wave-uniform -> scalar s_load (free of VALU/LDS pipes).
// Round-5 post-mortem: LDS-tiled GEMMs were LDS-ISSUE-bound (per CU-slab
// ~3000 LDS cyc vs 2048 VALU cyc; VALUBusy pinned ~22% across tilings,
// 3.6M bank conflicts). This removes the LDS pipe from the loop entirely.
template <bool AFF>
__global__ __launch_bounds__(256) void gemm_rd_t(const float* __restrict__ X, int sx, long xbs,
                                                 const float2* __restrict__ scb,
                                                 const float* __restrict__ Wt, int M, int K,
                                                 float* __restrict__ Out, int so, long obs) {
  int b = blockIdx.z;
  int n = blockIdx.x * 256 + threadIdx.x;
  int m0 = blockIdx.y * 16;
  const float* xr = X + (long)b * xbs + (long)n * sx;
  const float2* sc = AFF ? scb + b * K : nullptr;
  const float* wp = Wt + m0;
  float acc[16];
#pragma unroll
  for (int j = 0; j < 16; ++j) acc[j] = 0.f;
#pragma unroll 8
  for (int k0 = 0; k0 < K; k0 += 4) {
    float4 xv = *(const float4*)(xr + k0);
    if (AFF) {
      float2 a0 = sc[k0], a1 = sc[k0 + 1], a2 = sc[k0 + 2], a3 = sc[k0 + 3];
      AFFLK4(xv, a0, a1, a2, a3)
    }
    mac4(acc, xv, wp + (long)k0 * M, M);
  }
  float* ob = Out + (long)b * obs + (long)n * so + m0;
  *(float4*)(ob) = make_float4(acc[0], acc[1], acc[2], acc[3]);
  *(float4*)(ob + 4) = make_float4(acc[4], acc[5], acc[6], acc[7]);
  *(float4*)(ob + 8) = make_float4(acc[8], acc[9], acc[10], acc[11]);
  *(float4*)(ob + 12) = make_float4(acc[12], acc[13], acc[14], acc[15]);
}

// stage-4 row-dot GEMM: X = concat(x0 | leaky(aff1(ym1)) | leaky(aff2(ym2))),
// K=512, M=128. Three sequential k-segments, same per-thread structure.
__global__ __launch_bounds__(256) void gemm_rdcat_k(const float* __restrict__ x0b,
                                                    const float* __restrict__ ym1,
                                                    const float* __restrict__ ym2,
                                                    const float2* __restrict__ scb1,
                                                    const float2* __restrict__ scb2,
                                                    const float* __restrict__ Wt,
                                                    float* __restrict__ Out) {
  int b = blockIdx.z;
  int n = blockIdx.x * 256 + threadIdx.x;
  int m0 = blockIdx.y * 16;
  long nb = (long)b * NPTS + n;
  const float* wp = Wt + m0;
  float acc[16];
#pragma unroll
  for (int j = 0; j < 16; ++j) acc[j] = 0.f;
  {
    const float* xr = x0b + nb * 128;
#pragma unroll 8
    for (int k0 = 0; k0 < 128; k0 += 4) {
      float4 xv = *(const float4*)(xr + k0);
      mac4(acc, xv, wp + (long)k0 * 128, 128);
    }
  }
  {
    const float* xr = ym1 + nb * 128;
    const float2* sc = scb1 + b * 128;
#pragma unroll 8
    for (int k0 = 0; k0 < 128; k0 += 4) {
      float4 xv = *(const float4*)(xr + k0);
      float2 a0 = sc[k0], a1 = sc[k0 + 1], a2 = sc[k0 + 2], a3 = sc[k0 + 3];
      AFFLK4(xv, a0, a1, a2, a3)
      mac4(acc, xv, wp + (long)(128 + k0) * 128, 128);
    }
  }
  {
    const float* xr = ym2 + nb * 256;
    const float2* sc = scb2 + b * 256;
#pragma unroll 8
    for (int k0 = 0; k0 < 256; k0 += 4) {
      float4 xv = *(const float4*)(xr + k0);
      float2 a0 = sc[k0], a1 = sc[k0 + 1], a2 = sc[k0 + 2], a3 = sc[k0 + 3];
      AFFLK4(xv, a0, a1, a2, a3)
      mac4(acc, xv, wp + (long)(256 + k0) * 128, 128);
    }
  }
  float* ob = Out + nb * 128 + m0;
  *(float4*)(ob) = make_float4(acc[0], acc[1], acc[2], acc[3]);
  *(float4*)(ob + 4) = make_float4(acc[4], acc[5], acc[6], acc[7]);
  *(float4*)(ob + 8) = make_float4(acc[8], acc[9], acc[10], acc[11]);
  *(float4*)(ob + 12) = make_float4(acc[12], acc[13], acc[14], acc[15]);
}

// ---------------- edge (EXACT round-0 proven config): y = u[n] + v[idx[n,k]] ----
// max over k + channel sum/sumsq. PPB=32, 1024 blocks, 4 blocks/CU:
//   1024 blocks x 4 waves = 4096 waves = 256 CU x 16 waves -> EXACT full
//   residency, one wave-batch, zero block turnover; p-loop gives each wave
//   2 (stage2) / 4 (stage3) unrolled independent point-chains for MLP.
// (b, ct) in blk bits 1-2 -> each XCD sees a fixed (batch, channel-tile):
//   per-XCD gather table 2-4 MB = L2-resident.
// MEASURED A/B: PPB=16/2048 blocks = 114us; PPB=32/1024 = 70us; full-row
// CG=64 = 126us (L2 thrash). Do not perturb grid shape or ct split.
template <int CTILE, int PPB>
__global__ __launch_bounds__(256) void edge_max_t(const float* __restrict__ uv, int S, int voff,
                                                  int Cout, const int* __restrict__ idx,
                                                  float* __restrict__ ymax,
                                                  float* __restrict__ stats) {
  constexpr int CG = CTILE / 4;     // channel-groups (threads per point-row)
  constexpr int PSL = 256 / CG;     // point-slots per block
  __shared__ float ls[2][256][4];
  int blk = blockIdx.x;
  int c = (blk & 7) >> 1;           // combo 0..3
  int b = c >> 1;                   // batch
  int ct = c & 1;                   // channel tile
  int pblk = ((blk >> 3) << 1) | (blk & 1);
  int ch0 = ct * CTILE;
  const float* uvb = uv + (long)b * NPTS * S;
  const int* idxb = idx + (long)b * NPTS * KNN;
  float* ymb = ymax + (long)b * NPTS * Cout;
  int cg = threadIdx.x & (CG - 1);
  int ps = threadIdx.x / CG;
  int n0 = pblk * PPB;
  const float* vb = uvb + voff + ch0 + 4 * cg;
  float4 s = make_float4(0.f, 0.f, 0.f, 0.f);
  float4 s2 = make_float4(0.f, 0.f, 0.f, 0.f);
  for (int p = ps; p < PPB; p += PSL) {
    int n = n0 + p;
    const int* ip = idxb + n * KNN;
    int4 ia = *(const int4*)(ip);
    int4 ib4 = *(const int4*)(ip + 4);
    int4 ic = *(const int4*)(ip + 8);
    int4 id4 = *(const int4*)(ip + 12);
    int mi[KNN] = {ia.x, ia.y, ia.z, ia.w, ib4.x, ib4.y, ib4.z, ib4.w,
                   ic.x, ic.y, ic.z, ic.w, id4.x, id4.y, id4.z, id4.w};
    float4 u = *(const float4*)(uvb + (long)n * S + ch0 + 4 * cg);
    float4 mx = make_float4(-INFINITY, -INFINITY, -INFINITY, -INFINITY);
#pragma unroll
    for (int k = 0; k < KNN; ++k) {
      float4 v = *(const float4*)(vb + (long)mi[k] * S);
      float4 y;
      y.x = u.x + v.x; y.y = u.y + v.y; y.z = u.z + v.z; y.w = u.w + v.w;
      mx.x = fmaxf(mx.x, y.x); mx.y = fmaxf(mx.y, y.y);
      mx.z = fmaxf(mx.z, y.z); mx.w = fmaxf(mx.w, y.w);
      s.x += y.x; s.y += y.y; s.z += y.z; s.w += y.w;
      s2.x = fmaf(y.x, y.x, s2.x); s2.y = fmaf(y.y, y.y, s2.y);
      s2.z = fmaf(y.z, y.z, s2.z); s2.w = fmaf(y.w, y.w, s2.w);
    }
    *(float4*)(ymb + (long)n * Cout + ch0 + 4 * cg) = mx;
  }
  int t = threadIdx.x;
  ls[0][t][0] = s.x; ls[0][t][1] = s.y; ls[0][t][2] = s.z; ls[0][t][3] = s.w;
  ls[1][t][0] = s2.x; ls[1][t][1] = s2.y; ls[1][t][2] = s2.z; ls[1][t][3] = s2.w;
  __syncthreads();
  if (ps == 0) {
#pragma unroll
    for (int j = 1; j < PSL; ++j) {
      int q = j * CG + cg;
      s.x += ls[0][q][0]; s.y += ls[0][q][1]; s.z += ls[0][q][2]; s.w += ls[0][q][3];
      s2.x += ls[1][q][0]; s2.y += ls[1][q][1]; s2.z += ls[1][q][2]; s2.w += ls[1][q][3];
    }
    float* st = stats + ((long)b * Cout + ch0 + 4 * cg) * 2;
    atomicAdd(&st[0], s.x); atomicAdd(&st[1], s2.x);
    atomicAdd(&st[2], s.y); atomicAdd(&st[3], s2.y);
    atomicAdd(&st[4], s.z); atomicAdd(&st[5], s2.z);
    atomicAdd(&st[6], s.w); atomicAdd(&st[7], s2.w);
  }
}

// per-column (sum, sumsq) over y3 [B][N][128] -> stats (for stage-4 norm)
__global__ void colstats_k(const float* __restrict__ y3, float* __restrict__ stats) {
  int b = blockIdx.y;
  int o = threadIdx.x & 127, slot = threadIdx.x >> 7;
  int n0 = blockIdx.x * 64;
  float s = 0.f, s2 = 0.f;
  for (int p = slot; p < 64; p += 2) {
    float y = y3[((long)b * NPTS + n0 + p) * 128 + o];
    s += y;
    s2 = fmaf(y, y, s2);
  }
  float* st = stats + ((long)b * 128 + o) * 2;
  atomicAdd(&st[0], s);
  atomicAdd(&st[1], s2);
}

__global__ void final_k(const float* __restrict__ y3, const float* __restrict__ stats,
                        float* __restrict__ out) {
  __shared__ float tile[32][33];
  int b = blockIdx.z;
  int n0 = blockIdx.x * 32, o0 = blockIdx.y * 32;
  int tx = threadIdx.x;
  for (int ty = threadIdx.y; ty < 32; ty += 8) {
    int o = o0 + tx;
    const float* st = stats + ((long)b * 128 + o) * 2;
    float mean = st[0] * (1.f / 8192.f);
    float var = st[1] * (1.f / 8192.f) - mean * mean;
    float inv = rsqrtf(var + EPSI);
    float y = y3[((long)b * NPTS + n0 + ty) * 128 + o];
    float z = (y - mean) * inv;
    tile[ty][tx] = z >= 0.f ? z : SLOPE * z;
  }
  __syncthreads();
  for (int ty = threadIdx.y; ty < 32; ty += 8)
    out[((long)b * CH + o0 + ty) * NPTS + n0 + tx] = tile[tx][ty];
}

// ---------------- launch ----------------
extern "C" void kernel_launch(void* const* d_in, const int* in_sizes, int n_in,
                              void* d_out, int out_size, void* d_ws, size_t ws_size,
                              hipStream_t stream) {
  const float* coords = (const float*)d_in[0];
  const float* features = (const float*)d_in[1];
  const float* W1 = (const float*)d_in[2];
  const float* W2 = (const float*)d_in[3];
  const float* W3 = (const float*)d_in[4];
  float* out = (float*)d_out;
  char* ws = (char*)d_ws;

  int* idx = (int*)(ws + OFF_IDX);
  float* x0b = (float*)(ws + OFF_X0B);
  float* ym1 = (float*)(ws + OFF_YM1);
  float* ym2 = (float*)(ws + OFF_YM2);
  float* uv = (float*)(ws + OFF_UV);
  float* y4 = (float*)(ws + OFF_Y4);
  float2* surv = (float2*)(ws + OFF_SURV);
  float2* pa = (float2*)(ws + OFF_PA);
  int* counts = (int*)(ws + OFF_CNT);
  float* tau = (float*)(ws + OFF_TAU);
  float* wm1t = (float*)(ws + OFF_WM1T);
  float* wm2t = (float*)(ws + OFF_WM2T);
  float* w3t = (float*)(ws + OFF_W3T);
  float* stats = (float*)(ws + OFF_STATS);
  float2* scb1 = (float2*)(ws + OFF_SCB1);
  float2* scb2 = (float2*)(ws + OFF_SCB2);
  float4* pts4 = (float4*)(ws + OFF_PTS4);

  zero_stats_k<<<8, 256, 0, stream>>>(stats);
  // ---- KNN ----
  knn_prep_k<<<dim3(NPTS / 256, NB), 256, 0, stream>>>(coords, pts4);
  knn_phaseA_k<<<dim3(1024, NB), 256, 0, stream>>>(pts4, pa);
  knn_mergeA_k<<<dim3(NPTS / 256, NB), 256, 0, stream>>>(pa, tau);
  knn_filter_k<<<dim3(NPTS / 256, NCH, NB), 256, 0, stream>>>(pts4, tau, surv, counts);
  knn_mergeB_k<<<dim3(NPTS / 32, NB), 256, 0, stream>>>(surv, counts, pts4, idx);

  transpose_x0_k<<<dim3(NPTS / 32, CH / 32, NB), dim3(32, 8), 0, stream>>>(features, x0b);
  prep_wt_k<<<640, 256, 0, stream>>>(W1, W2, W3, wm1t, wm2t, w3t);

  // stage 2: M=256, K=128; grid (32 n-tiles, 16 m-tiles, 2) = 1024 blocks
  gemm_rd_t<false><<<dim3(NPTS / 256, 16, NB), 256, 0, stream>>>(
      x0b, 128, (long)NPTS * 128, nullptr, wm1t, 256, 128, uv, 256, (long)NPTS * 256);
  edge_max_t<64, 32><<<dim3(NPTS / 32 * 2 * NB), 256, 0, stream>>>(uv, 256, 128, 128, idx,
                                                                   ym1, stats);
  finalize_scb_k<<<1, 256, 0, stream>>>(stats, scb1, 256, 1.0f / 131072.0f);
  // stage 3: M=512, K=128, affine-staged X; grid (32, 32, 2) = 2048 blocks
  gemm_rd_t<true><<<dim3(NPTS / 256, 32, NB), 256, 0, stream>>>(
      ym1, 128, (long)NPTS * 128, scb1, wm2t, 512, 128, uv, 512, (long)NPTS * 512);
  edge_max_t<128, 32><<<dim3(NPTS / 32 * 2 * NB), 256, 0, stream>>>(uv, 512, 256, 256, idx,
                                                                    ym2, stats + 512);
  finalize_scb_k<<<2, 256, 0, stream>>>(stats + 512, scb2, 512, 1.0f / 131072.0f);
  // stage 4: M=128, K=512 (concat); grid (32, 8, 2) = 512 blocks
  gemm_rdcat_k<<<dim3(NPTS / 256, 8, NB), 256, 0, stream>>>(x0b, ym1, ym2, scb1, scb2, w3t,
                                                            y4);
  colstats_k<<<dim3(NPTS / 64, NB), 256, 0, stream>>>(y4, stats + 1536);
  final_k<<<dim3(NPTS / 32, CH / 32, NB), dim3(32, 8), 0, stream>>>(y4, stats + 1536, out);
}

// Round 7
// 487.178 us; speedup vs baseline: 1.0930x; 1.0930x over previous
//
#include <hip/hip_runtime.h>
#include <math.h>

#define NB 2
#define NPTS 8192
#define CH 128
#define KNN 16
#define K17 17
#define EPSI 1e-5f
#define SLOPE 0.2f
#define NCH 32        // filter chunks
#define CHSZ 256      // candidates per chunk
#define SCAP 16       // survivor cap per chunk
#define BIGF 3.0e38f

// ---------------- workspace layout (bytes) ----------------
// idx  [B][N][16] int            @ 0            (1 MB)
// x0b  [B][N][128] f32           @ 1,048,576    (8 MB)   } surv aliases
// ym1  [B][N][128] f32           @ 9,437,184    (8 MB)
// ym2  [B][N][256] f32           @ 17,825,792   (16 MB)
// uv   [B][N][512] f32           @ 34,603,008   (32 MB)  } stage-4: y4b partial (8MB)
// y4   [B][N][128] f32           @ 68,157,440   (8 MB)   } pa aliases y4
// counts [B][N][32] int          @ 76,546,048   (2 MB)
// tau                            @ 78,643,200   (64 KB)
// Wm1 [256][128]                 @ 78,708,736
// Wm2 [512][128]                 @ 78,839,808
// stats (2048 f32)               @ 79,101,952
// scb1 [B][128] float2           @ 79,110,144
// scb2 [B][256] float2           @ 79,112,192
// pts4 [B][N] float4             @ 79,116,288
#define OFF_IDX   0L
#define OFF_X0B   1048576L
#define OFF_YM1   9437184L
#define OFF_YM2   17825792L
#define OFF_UV    34603008L
#define OFF_Y4    68157440L
#define OFF_SURV  OFF_X0B
#define OFF_PA    OFF_Y4
#define OFF_CNT   76546048L
#define OFF_TAU   78643200L
#define OFF_WM1   78708736L
#define OFF_WM2   78839808L
#define OFF_STATS 79101952L
#define OFF_SCB1  79110144L
#define OFF_SCB2  79112192L
#define OFF_PTS4  79116288L

// ---------------- small utility kernels ----------------

__global__ void zero_stats_k(float* __restrict__ stats) {
  int t = blockIdx.x * 256 + threadIdx.x;
  if (t < 2048) stats[t] = 0.f;
}

// features [B][128][N] -> x0b[b][n][0:128]
__global__ void transpose_x0_k(const float* __restrict__ feat, float* __restrict__ x0b) {
  __shared__ float tile[32][33];
  int b = blockIdx.z;
  int n0 = blockIdx.x * 32, c0 = blockIdx.y * 32;
  int tx = threadIdx.x;
  for (int ty = threadIdx.y; ty < 32; ty += 8)
    tile[ty][tx] = feat[((long)b * CH + c0 + ty) * NPTS + n0 + tx];
  __syncthreads();
  for (int ty = threadIdx.y; ty < 32; ty += 8)
    x0b[((long)b * NPTS + n0 + ty) * 128 + c0 + tx] = tile[tx][ty];
}

__global__ void prep_w_k(const float* __restrict__ W1, const float* __restrict__ W2,
                         float* __restrict__ Wm1, float* __restrict__ Wm2) {
  int t = blockIdx.x * 256 + threadIdx.x;
  if (t < 256 * 128) {
    int r = t >> 7, k = t & 127;
    Wm1[t] = (r < 128) ? (W1[r * 256 + k] - W1[r * 256 + 128 + k])
                       : W1[(r - 128) * 256 + 128 + k];
  }
  if (t < 512 * 128) {
    int r = t >> 7, k = t & 127;
    Wm2[t] = (r < 256) ? (W2[r * 256 + k] - W2[r * 256 + 128 + k])
                       : W2[(r - 256) * 256 + 128 + k];
  }
}

// sums (sum, sumsq) -> (scale, bias) per (b, col):  z = y*scale + bias
__global__ void finalize_scb_k(const float* __restrict__ stats, float2* __restrict__ scb,
                               int count, float cinv) {
  int t = blockIdx.x * 256 + threadIdx.x;
  if (t < count) {
    float mean = stats[t * 2] * cinv;
    float var = stats[t * 2 + 1] * cinv - mean * mean;
    float inv = rsqrtf(var + EPSI);
    scb[t] = make_float2(inv, -mean * inv);
  }
}

// ---------------- KNN ----------------
__global__ void knn_prep_k(const float* __restrict__ coords, float4* __restrict__ pts) {
  int b = blockIdx.y;
  int i = blockIdx.x * 256 + threadIdx.x;
  const float* cb = coords + (long)b * 3 * NPTS;
  float x = cb[i], y = cb[NPTS + i], z = cb[2 * NPTS + i];
  float sq = __fadd_rn(__fadd_rn(__fmul_rn(x, x), __fmul_rn(y, y)), __fmul_rn(z, z));
  pts[(long)b * NPTS + i] = make_float4(x, y, z, sq);
}

#define DIST(pi, pj, d2)                                                          \
  float dot = __fadd_rn(__fadd_rn(__fmul_rn((pi).x, (pj).x), __fmul_rn((pi).y, (pj).y)), \
                        __fmul_rn((pi).z, (pj).z));                               \
  float d2 = __fsub_rn(__fadd_rn((pi).w, (pj).w), __fmul_rn(2.0f, dot));

// Stable predicated insertion into ascending (d, id) list; ties keep earlier insert.
#define KNN_INSERT(d2v, jv)                                              \
  if ((d2v) < d[K17 - 1]) {                                              \
    _Pragma("unroll")                                                    \
    for (int s = K17 - 1; s > 0; --s) {                                  \
      if ((d2v) < d[s - 1]) { d[s] = d[s - 1]; id[s] = id[s - 1]; }      \
      else if ((d2v) < d[s]) { d[s] = (d2v); id[s] = (jv); }             \
    }                                                                    \
    if ((d2v) < d[0]) { d[0] = (d2v); id[0] = (jv); }                    \
  }

// Phase A: 32 sub-threads per point; sub s keeps top-2 of sample candidates
// j in [s*64, s*64+64) (sample = first 2048 points).
__global__ __launch_bounds__(256) void knn_phaseA_k(const float4* __restrict__ pts,
                                                    float2* __restrict__ pa) {
  int b = blockIdx.y;
  int ib = blockIdx.x & 127;
  int sg = blockIdx.x >> 7;          // 0..7
  int i = ib * 64 + (threadIdx.x & 63);
  int sub = sg * 4 + (threadIdx.x >> 6);   // 0..31
  const float4* P = pts + (long)b * NPTS;
  float4 pi = P[i];
  float d0 = BIGF, d1 = BIGF;
  int i0 = 0x7fffffff, i1 = 0x7fffffff;
  int j0 = sub * 64;
  for (int jj = 0; jj < 64; ++jj) {
    float4 pj = P[j0 + jj];
    DIST(pi, pj, d2)
    if (d2 < d1) {
      if (d2 < d0) { d1 = d0; i1 = i0; d0 = d2; i0 = j0 + jj; }
      else { d1 = d2; i1 = j0 + jj; }
    }
  }
  long base = (((long)b * NPTS + i) * 32 + sub) * 2;
  pa[base] = make_float2(d0, __int_as_float(i0));
  pa[base + 1] = make_float2(d1, __int_as_float(i1));
}

// Merge 32x2 partials -> tau = 17th smallest of the 64 sample distances
__global__ __launch_bounds__(256) void knn_mergeA_k(const float2* __restrict__ pa,
                                                    float* __restrict__ tau) {
  int b = blockIdx.y;
  int i = blockIdx.x * 256 + threadIdx.x;
  float d[K17]; int id[K17];
#pragma unroll
  for (int s = 0; s < K17; ++s) { d[s] = BIGF; id[s] = 0x7fffffff; }
  long base = ((long)b * NPTS + i) * 64;
  for (int c = 0; c < 64; ++c) {
    float2 v = pa[base + c];
    if (v.x < d[K17 - 1]) {
      int j = __float_as_int(v.y);
      KNN_INSERT(v.x, j);
    }
  }
  tau[(long)b * NPTS + i] = d[K17 - 1];
}

// Phase B: per (i, chunk) thread, append all candidates with d2 <= tau_i.
__global__ __launch_bounds__(256) void knn_filter_k(const float4* __restrict__ pts,
                                                    const float* __restrict__ tau,
                                                    float2* __restrict__ surv,
                                                    int* __restrict__ counts) {
  int b = blockIdx.z;
  int i = blockIdx.x * 256 + threadIdx.x;
  int chunk = blockIdx.y;
  const float4* P = pts + (long)b * NPTS;
  float4 pi = P[i];
  float t = tau[(long)b * NPTS + i];
  long sbase = (((long)b * NPTS + i) * NCH + chunk) * SCAP;
  int cnt = 0;
  int j0 = chunk * CHSZ;
#pragma unroll 2
  for (int jj = 0; jj < CHSZ; ++jj) {
    float4 pj = P[j0 + jj];
    DIST(pi, pj, d2)
    if (d2 <= t) {
      if (cnt < SCAP) surv[sbase + cnt] = make_float2(d2, __int_as_float(j0 + jj));
      cnt++;
    }
  }
  counts[((long)b * NPTS + i) * NCH + chunk] = cnt;
}

// Fused Merge-B: block = 32 points x 8 subs, each sub merges 4 chunks into a
// register top-17, 3-level LDS insert-merge tree.
__global__ __launch_bounds__(256) void knn_mergeB_k(const float2* __restrict__ surv,
                                                    const int* __restrict__ counts,
                                                    const float4* __restrict__ pts,
                                                    int* __restrict__ idxo) {
  __shared__ float2 lds[8][K17][32];
  int b = blockIdx.y;
  int pl = threadIdx.x & 31;
  int sub = threadIdx.x >> 5;
  int i = blockIdx.x * 32 + pl;
  const float4* P = pts + (long)b * NPTS;
  float4 pi = P[i];
  float d[K17]; int id[K17];
#pragma unroll
  for (int s = 0; s < K17; ++s) { d[s] = BIGF; id[s] = 0x7fffffff; }
  long cbase = ((long)b * NPTS + i) * NCH;
  int4 c4 = *(const int4*)(counts + cbase + sub * 4);
  int cnt4[4] = {c4.x, c4.y, c4.z, c4.w};
#pragma unroll
  for (int q = 0; q < 4; ++q) {
    int c = sub * 4 + q;
    int cnt = cnt4[q];
    if (cnt > SCAP) {
      int j0 = c * CHSZ;
      for (int jj = 0; jj < CHSZ; ++jj) {
        float4 pj = P[j0 + jj];
        DIST(pi, pj, d2)
        KNN_INSERT(d2, j0 + jj);
      }
    } else {
      long sb = (cbase + c) * SCAP;
      for (int p = 0; p < cnt; p += 2) {
        float4 v2 = *(const float4*)(surv + sb + p);
        if (v2.x < d[K17 - 1]) {
          int j = __float_as_int(v2.y);
          KNN_INSERT(v2.x, j);
        }
        if (p + 1 < cnt && v2.z < d[K17 - 1]) {
          int j = __float_as_int(v2.w);
          KNN_INSERT(v2.z, j);
        }
      }
    }
  }
#pragma unroll
  for (int s = 0; s < K17; ++s) lds[sub][s][pl] = make_float2(d[s], __int_as_float(id[s]));
  __syncthreads();
  if ((sub & 1) == 0) {
#pragma unroll
    for (int s = 0; s < K17; ++s) {
      float2 v = lds[sub + 1][s][pl];
      if (v.x < d[K17 - 1]) {
        int j = __float_as_int(v.y);
        KNN_INSERT(v.x, j);
      }
    }
  }
  __syncthreads();
  if ((sub & 1) == 0) {
#pragma unroll
    for (int s = 0; s < K17; ++s) lds[sub >> 1][s][pl] = make_float2(d[s], __int_as_float(id[s]));
  }
  __syncthreads();
  if (sub < 2) {
#pragma unroll
    for (int s = 0; s < K17; ++s) {
      float2 v = lds[2 * sub][s][pl];
      d[s] = v.x; id[s] = __float_as_int(v.y);
    }
#pragma unroll
    for (int s = 0; s < K17; ++s) {
      float2 v = lds[2 * sub + 1][s][pl];
      if (v.x < d[K17 - 1]) {
        int j = __float_as_int(v.y);
        KNN_INSERT(v.x, j);
      }
    }
  }
  __syncthreads();
  if (sub < 2) {
#pragma unroll
    for (int s = 0; s < K17; ++s) lds[sub][s][pl] = make_float2(d[s], __int_as_float(id[s]));
  }
  __syncthreads();
  if (sub == 0) {
#pragma unroll
    for (int s = 0; s < K17; ++s) {
      float2 v = lds[0][s][pl];
      d[s] = v.x; id[s] = __float_as_int(v.y);
    }
#pragma unroll
    for (int s = 0; s < K17; ++s) {
      float2 v = lds[1][s][pl];
      if (v.x < d[K17 - 1]) {
        int j = __float_as_int(v.y);
        KNN_INSERT(v.x, j);
      }
    }
    long ob = ((long)b * NPTS + i) * KNN;
#pragma unroll
    for (int s = 1; s < K17; ++s) idxo[ob + s - 1] = id[s];
  }
}

// ---------------- GEMM: Out[b][n][m] = sum_k X[b][n][k] * W[m][k] ----------------
#define GBN 128
#define GBM 64
#define GBK 32
__global__ __launch_bounds__(256) void gemm_xt_k(const float* __restrict__ X, int sx, long xbs,
                                                 const float* __restrict__ W, int K,
                                                 float* __restrict__ Out, int so, long obs) {
  __shared__ float Xs[GBK][GBN + 4];
  __shared__ float Ws[GBK][GBM + 4];
  int b = blockIdx.z;
  const float* Xb = X + (long)b * xbs;
  float* Ob = Out + (long)b * obs;
  int n0 = blockIdx.x * GBN, m0 = blockIdx.y * GBM;
  int tx = threadIdx.x, ty = threadIdx.y;
  int tid = ty * 16 + tx;
  float acc[8][4];
#pragma unroll
  for (int i = 0; i < 8; ++i)
#pragma unroll
    for (int j = 0; j < 4; ++j) acc[i][j] = 0.f;

  for (int k0 = 0; k0 < K; k0 += GBK) {
#pragma unroll
    for (int i = 0; i < 4; ++i) {
      int q = tid + i * 256;
      int r = q >> 3, kq = (q & 7) * 4;
      const float4 v = *(const float4*)(Xb + (long)(n0 + r) * sx + k0 + kq);
      Xs[kq][r] = v.x; Xs[kq + 1][r] = v.y; Xs[kq + 2][r] = v.z; Xs[kq + 3][r] = v.w;
    }
#pragma unroll
    for (int i = 0; i < 2; ++i) {
      int q = tid + i * 256;
      int r = q >> 3, kq = (q & 7) * 4;
      const float4 v = *(const float4*)(W + (long)(m0 + r) * K + k0 + kq);
      Ws[kq][r] = v.x; Ws[kq + 1][r] = v.y; Ws[kq + 2][r] = v.z; Ws[kq + 3][r] = v.w;
    }
    __syncthreads();
#pragma unroll
    for (int kk = 0; kk < GBK; ++kk) {
      float4 w4 = *(const float4*)&Ws[kk][tx * 4];
      float4 xa = *(const float4*)&Xs[kk][ty * 8];
      float4 xb4 = *(const float4*)&Xs[kk][ty * 8 + 4];
      float xs[8] = {xa.x, xa.y, xa.z, xa.w, xb4.x, xb4.y, xb4.z, xb4.w};
      float wv[4] = {w4.x, w4.y, w4.z, w4.w};
#pragma unroll
      for (int i = 0; i < 8; ++i)
#pragma unroll
        for (int j = 0; j < 4; ++j) acc[i][j] = fmaf(xs[i], wv[j], acc[i][j]);
    }
    __syncthreads();
  }
#pragma unroll
  for (int i = 0; i < 8; ++i) {
    float4 v = make_float4(acc[i][0], acc[i][1], acc[i][2], acc[i][3]);
    *(float4*)(Ob + (long)(n0 + ty * 8 + i) * so + m0 + tx * 4) = v;
  }
}

#define AFFLK4(v, a0, a1, a2, a3)                              \
  v.x = fmaf(v.x, a0.x, a0.y); v.x = fmaxf(v.x, SLOPE * v.x);  \
  v.y = fmaf(v.y, a1.x, a1.y); v.y = fmaxf(v.y, SLOPE * v.y);  \
  v.z = fmaf(v.z, a2.x, a2.y); v.z = fmaxf(v.z, SLOPE * v.z);  \
  v.w = fmaf(v.w, a3.x, a3.y); v.w = fmaxf(v.w, SLOPE * v.w);

// stage-3 GEMM: X = leaky(affine(ym1)) applied during staging. K=128, X stride 128.
__global__ __launch_bounds__(256) void gemm_aff_k(const float* __restrict__ X,
                                                  const float2* __restrict__ scb,
                                                  const float* __restrict__ W,
                                                  float* __restrict__ Out, int so, long obs) {
  __shared__ float Xs[GBK][GBN + 4];
  __shared__ float Ws[GBK][GBM + 4];
  int b = blockIdx.z;
  const float* Xb = X + (long)b * NPTS * 128;
  const float2* sc = scb + b * 128;
  float* Ob = Out + (long)b * obs;
  int n0 = blockIdx.x * GBN, m0 = blockIdx.y * GBM;
  int tx = threadIdx.x, ty = threadIdx.y;
  int tid = ty * 16 + tx;
  float acc[8][4];
#pragma unroll
  for (int i = 0; i < 8; ++i)
#pragma unroll
    for (int j = 0; j < 4; ++j) acc[i][j] = 0.f;

  for (int k0 = 0; k0 < 128; k0 += GBK) {
#pragma unroll
    for (int i = 0; i < 4; ++i) {
      int q = tid + i * 256;
      int r = q >> 3, kq = (q & 7) * 4;
      float4 v = *(const float4*)(Xb + (long)(n0 + r) * 128 + k0 + kq);
      float2 a0 = sc[k0 + kq], a1 = sc[k0 + kq + 1], a2 = sc[k0 + kq + 2], a3 = sc[k0 + kq + 3];
      AFFLK4(v, a0, a1, a2, a3)
      Xs[kq][r] = v.x; Xs[kq + 1][r] = v.y; Xs[kq + 2][r] = v.z; Xs[kq + 3][r] = v.w;
    }
#pragma unroll
    for (int i = 0; i < 2; ++i) {
      int q = tid + i * 256;
      int r = q >> 3, kq = (q & 7) * 4;
      const float4 v = *(const float4*)(W + (long)(m0 + r) * 128 + k0 + kq);
      Ws[kq][r] = v.x; Ws[kq + 1][r] = v.y; Ws[kq + 2][r] = v.z; Ws[kq + 3][r] = v.w;
    }
    __syncthreads();
#pragma unroll
    for (int kk = 0; kk < GBK; ++kk) {
      float4 w4 = *(const float4*)&Ws[kk][tx * 4];
      float4 xa = *(const float4*)&Xs[kk][ty * 8];
      float4 xb4 = *(const float4*)&Xs[kk][ty * 8 + 4];
      float xs[8] = {xa.x, xa.y, xa.z, xa.w, xb4.x, xb4.y, xb4.z, xb4.w};
      float wv[4] = {w4.x, w4.y, w4.z, w4.w};
#pragma unroll
      for (int i = 0; i < 8; ++i)
#pragma unroll
        for (int j = 0; j < 4; ++j) acc[i][j] = fmaf(xs[i], wv[j], acc[i][j]);
    }
    __syncthreads();
  }
#pragma unroll
  for (int i = 0; i < 8; ++i) {
    float4 v = make_float4(acc[i][0], acc[i][1], acc[i][2], acc[i][3]);
    *(float4*)(Ob + (long)(n0 + ty * 8 + i) * so + m0 + tx * 4) = v;
  }
}

// stage-4 GEMM, ROUND-7: 128n x 64m tile (8x4/thread, 3 b128-reads per 32 FMA —
// best LDS-instr/FLOP ratio of the shapes tried) + SPLIT-K 2-way so the grid is
// (64, 2mt x 2kh, 2) = 512 blocks = 2 blocks/CU (round-4 showed 128x64 without
// split-K = 256 blocks = 1 block/CU -> nothing overlaps the staging/barrier
// phases -> 74us; round-5 64x64 had 2 blocks/CU but 2x the LDS reads -> 78us).
// k-half 0 = x0b(k<128) + ym1(128..256); k-half 1 = ym2(256..512) — the split
// lands exactly on segment boundaries. Partials: kh0 -> y4, kh1 -> y4b (dead uv
// buffer). colstats2_k sums the halves, writes y4, accumulates column stats.
__global__ __launch_bounds__(256) void gemm_cat_k(const float* __restrict__ x0b,
                                                  const float* __restrict__ ym1,
                                                  const float* __restrict__ ym2,
                                                  const float2* __restrict__ scb1,
                                                  const float2* __restrict__ scb2,
                                                  const float* __restrict__ W,
                                                  float* __restrict__ OutA,
                                                  float* __restrict__ OutB) {
  __shared__ float Xs[GBK][GBN + 4];
  __shared__ float Ws[GBK][GBM + 4];
  int b = blockIdx.z;
  int mt = blockIdx.y & 1;
  int kh = blockIdx.y >> 1;
  float* Ob = (kh ? OutB : OutA) + (long)b * NPTS * 128;
  int n0 = blockIdx.x * GBN, m0 = mt * GBM;
  int tx = threadIdx.x, ty = threadIdx.y;
  int tid = ty * 16 + tx;
  float acc[8][4];
#pragma unroll
  for (int i = 0; i < 8; ++i)
#pragma unroll
    for (int j = 0; j < 4; ++j) acc[i][j] = 0.f;

  for (int ks = 0; ks < 8; ++ks) {
    int k0 = kh * 256 + ks * GBK;
    const float* Xb; long st_; const float2* sc_; int cb_;
    if (k0 < 128)      { Xb = x0b + (long)b * NPTS * 128; st_ = 128; sc_ = nullptr;        cb_ = 0; }
    else if (k0 < 256) { Xb = ym1 + (long)b * NPTS * 128; st_ = 128; sc_ = scb1 + b * 128; cb_ = 128; }
    else               { Xb = ym2 + (long)b * NPTS * 256; st_ = 256; sc_ = scb2 + b * 256; cb_ = 256; }
    int kl = k0 - cb_;
#pragma unroll
    for (int i = 0; i < 4; ++i) {
      int q = tid + i * 256;
      int r = q >> 3, kq = (q & 7) * 4;
      float4 v = *(const float4*)(Xb + (long)(n0 + r) * st_ + kl + kq);
      if (sc_) {
        float2 a0 = sc_[kl + kq], a1 = sc_[kl + kq + 1], a2 = sc_[kl + kq + 2], a3 = sc_[kl + kq + 3];
        AFFLK4(v, a0, a1, a2, a3)
      }
      Xs[kq][r] = v.x; Xs[kq + 1][r] = v.y; Xs[kq + 2][r] = v.z; Xs[kq + 3][r] = v.w;
    }
#pragma unroll
    for (int i = 0; i < 2; ++i) {
      int q = tid + i * 256;
      int r = q >> 3, kq = (q & 7) * 4;
      const float4 v = *(const float4*)(W + (long)(m0 + r) * 512 + k0 + kq);
      Ws[kq][r] = v.x; Ws[kq + 1][r] = v.y; Ws[kq + 2][r] = v.z; Ws[kq + 3][r] = v.w;
    }
    __syncthreads();
#pragma unroll
    for (int kk = 0; kk < GBK; ++kk) {
      float4 w4 = *(const float4*)&Ws[kk][tx * 4];
      float4 xa = *(const float4*)&Xs[kk][ty * 8];
      float4 xb4 = *(const float4*)&Xs[kk][ty * 8 + 4];
      float xs[8] = {xa.x, xa.y, xa.z, xa.w, xb4.x, xb4.y, xb4.z, xb4.w};
      float wv[4] = {w4.x, w4.y, w4.z, w4.w};
#pragma unroll
      for (int i = 0; i < 8; ++i)
#pragma unroll
        for (int j = 0; j < 4; ++j) acc[i][j] = fmaf(xs[i], wv[j], acc[i][j]);
    }
    __syncthreads();
  }
#pragma unroll
  for (int i = 0; i < 8; ++i) {
    float4 v = make_float4(acc[i][0], acc[i][1], acc[i][2], acc[i][3]);
    *(float4*)(Ob + (long)(n0 + ty * 8 + i) * 128 + m0 + tx * 4) = v;
  }
}

// ---------------- edge (EXACT round-0 proven config): y = u[n] + v[idx[n,k]] ----
// max over k + channel sum/sumsq. PPB=32, 1024 blocks, 4 blocks/CU:
//   1024 blocks x 4 waves = 4096 waves = 256 CU x 16 waves -> EXACT full
//   residency, one wave-batch, zero block turnover; p-loop gives each wave
//   2 (stage2) / 4 (stage3) unrolled independent point-chains for MLP.
// (b, ct) in blk bits 1-2 -> each XCD sees a fixed (batch, channel-tile):
//   per-XCD gather table 2-4 MB = L2-resident.
// MEASURED A/B: PPB=16/2048 blocks = 114us; PPB=32/1024 = 70us; full-row
// CG=64 = 126us (L2 thrash). Do not perturb grid shape or ct split.
template <int CTILE, int PPB>
__global__ __launch_bounds__(256) void edge_max_t(const float* __restrict__ uv, int S, int voff,
                                                  int Cout, const int* __restrict__ idx,
                                                  float* __restrict__ ymax,
                                                  float* __restrict__ stats) {
  constexpr int CG = CTILE / 4;     // channel-groups (threads per point-row)
  constexpr int PSL = 256 / CG;     // point-slots per block
  __shared__ float ls[2][256][4];
  int blk = blockIdx.x;
  int c = (blk & 7) >> 1;           // combo 0..3
  int b = c >> 1;                   // batch
  int ct = c & 1;                   // channel tile
  int pblk = ((blk >> 3) << 1) | (blk & 1);
  int ch0 = ct * CTILE;
  const float* uvb = uv + (long)b * NPTS * S;
  const int* idxb = idx + (long)b * NPTS * KNN;
  float* ymb = ymax + (long)b * NPTS * Cout;
  int cg = threadIdx.x & (CG - 1);
  int ps = threadIdx.x / CG;
  int n0 = pblk * PPB;
  const float* vb = uvb + voff + ch0 + 4 * cg;
  float4 s = make_float4(0.f, 0.f, 0.f, 0.f);
  float4 s2 = make_float4(0.f, 0.f, 0.f, 0.f);
  for (int p = ps; p < PPB; p += PSL) {
    int n = n0 + p;
    const int* ip = idxb + n * KNN;
    int4 ia = *(const int4*)(ip);
    int4 ib4 = *(const int4*)(ip + 4);
    int4 ic = *(const int4*)(ip + 8);
    int4 id4 = *(const int4*)(ip + 12);
    int mi[KNN] = {ia.x, ia.y, ia.z, ia.w, ib4.x, ib4.y, ib4.z, ib4.w,
                   ic.x, ic.y, ic.z, ic.w, id4.x, id4.y, id4.z, id4.w};
    float4 u = *(const float4*)(uvb + (long)n * S + ch0 + 4 * cg);
    float4 mx = make_float4(-INFINITY, -INFINITY, -INFINITY, -INFINITY);
#pragma unroll
    for (int k = 0; k < KNN; ++k) {
      float4 v = *(const float4*)(vb + (long)mi[k] * S);
      float4 y;
      y.x = u.x + v.x; y.y = u.y + v.y; y.z = u.z + v.z; y.w = u.w + v.w;
      mx.x = fmaxf(mx.x, y.x); mx.y = fmaxf(mx.y, y.y);
      mx.z = fmaxf(mx.z, y.z); mx.w = fmaxf(mx.w, y.w);
      s.x += y.x; s.y += y.y; s.z += y.z; s.w += y.w;
      s2.x = fmaf(y.x, y.x, s2.x); s2.y = fmaf(y.y, y.y, s2.y);
      s2.z = fmaf(y.z, y.z, s2.z); s2.w = fmaf(y.w, y.w, s2.w);
    }
    *(float4*)(ymb + (long)n * Cout + ch0 + 4 * cg) = mx;
  }
  int t = threadIdx.x;
  ls[0][t][0] = s.x; ls[0][t][1] = s.y; ls[0][t][2] = s.z; ls[0][t][3] = s.w;
  ls[1][t][0] = s2.x; ls[1][t][1] = s2.y; ls[1][t][2] = s2.z; ls[1][t][3] = s2.w;
  __syncthreads();
  if (ps == 0) {
#pragma unroll
    for (int j = 1; j < PSL; ++j) {
      int q = j * CG + cg;
      s.x += ls[0][q][0]; s.y += ls[0][q][1]; s.z += ls[0][q][2]; s.w += ls[0][q][3];
      s2.x += ls[1][q][0]; s2.y += ls[1][q][1]; s2.z += ls[1][q][2]; s2.w += ls[1][q][3];
    }
    float* st = stats + ((long)b * Cout + ch0 + 4 * cg) * 2;
    atomicAdd(&st[0], s.x); atomicAdd(&st[1], s2.x);
    atomicAdd(&st[2], s.y); atomicAdd(&st[3], s2.y);
    atomicAdd(&st[4], s.z); atomicAdd(&st[5], s2.z);
    atomicAdd(&st[6], s.w); atomicAdd(&st[7], s2.w);
  }
}

// sum split-K halves -> y4; per-column (sum, sumsq) -> stats
__global__ void colstats2_k(float* __restrict__ y4, const float* __restrict__ y4b,
                            float* __restrict__ stats) {
  int b = blockIdx.y;
  int o = threadIdx.x & 127, slot = threadIdx.x >> 7;
  int n0 = blockIdx.x * 64;
  float s = 0.f, s2 = 0.f;
  for (int p = slot; p < 64; p += 2) {
    long off = ((long)b * NPTS + n0 + p) * 128 + o;
    float y = y4[off] + y4b[off];
    y4[off] = y;
    s += y;
    s2 = fmaf(y, y, s2);
  }
  float* st = stats + ((long)b * 128 + o) * 2;
  atomicAdd(&st[0], s);
  atomicAdd(&st[1], s2);
}

__global__ void final_k(const float* __restrict__ y3, const float* __restrict__ stats,
                        float* __restrict__ out) {
  __shared__ float tile[32][33];
  int b = blockIdx.z;
  int n0 = blockIdx.x * 32, o0 = blockIdx.y * 32;
  int tx = threadIdx.x;
  for (int ty = threadIdx.y; ty < 32; ty += 8) {
    int o = o0 + tx;
    const float* st = stats + ((long)b * 128 + o) * 2;
    float mean = st[0] * (1.f / 8192.f);
    float var = st[1] * (1.f / 8192.f) - mean * mean;
    float inv = rsqrtf(var + EPSI);
    float y = y3[((long)b * NPTS + n0 + ty) * 128 + o];
    float z = (y - mean) * inv;
    tile[ty][tx] = z >= 0.f ? z : SLOPE * z;
  }
  __syncthreads();
  for (int ty = threadIdx.y; ty < 32; ty += 8)
    out[((long)b * CH + o0 + ty) * NPTS + n0 + tx] = tile[tx][ty];
}

// ---------------- launch ----------------
extern "C" void kernel_launch(void* const* d_in, const int* in_sizes, int n_in,
                              void* d_out, int out_size, void* d_ws, size_t ws_size,
                              hipStream_t stream) {
  const float* coords = (const float*)d_in[0];
  const float* features = (const float*)d_in[1];
  const float* W1 = (const float*)d_in[2];
  const float* W2 = (const float*)d_in[3];
  const float* W3 = (const float*)d_in[4];
  float* out = (float*)d_out;
  char* ws = (char*)d_ws;

  int* idx = (int*)(ws + OFF_IDX);
  float* x0b = (float*)(ws + OFF_X0B);
  float* ym1 = (float*)(ws + OFF_YM1);
  float* ym2 = (float*)(ws + OFF_YM2);
  float* uv = (float*)(ws + OFF_UV);
  float* y4 = (float*)(ws + OFF_Y4);
  float2* surv = (float2*)(ws + OFF_SURV);
  float2* pa = (float2*)(ws + OFF_PA);
  int* counts = (int*)(ws + OFF_CNT);
  float* tau = (float*)(ws + OFF_TAU);
  float* wm1 = (float*)(ws + OFF_WM1);
  float* wm2 = (float*)(ws + OFF_WM2);
  float* stats = (float*)(ws + OFF_STATS);
  float2* scb1 = (float2*)(ws + OFF_SCB1);
  float2* scb2 = (float2*)(ws + OFF_SCB2);
  float4* pts4 = (float4*)(ws + OFF_PTS4);

  zero_stats_k<<<8, 256, 0, stream>>>(stats);
  // ---- KNN ----
  knn_prep_k<<<dim3(NPTS / 256, NB), 256, 0, stream>>>(coords, pts4);
  knn_phaseA_k<<<dim3(1024, NB), 256, 0, stream>>>(pts4, pa);
  knn_mergeA_k<<<dim3(NPTS / 256, NB), 256, 0, stream>>>(pa, tau);
  knn_filter_k<<<dim3(NPTS / 256, NCH, NB), 256, 0, stream>>>(pts4, tau, surv, counts);
  knn_mergeB_k<<<dim3(NPTS / 32, NB), 256, 0, stream>>>(surv, counts, pts4, idx);

  transpose_x0_k<<<dim3(NPTS / 32, CH / 32, NB), dim3(32, 8), 0, stream>>>(features, x0b);
  prep_w_k<<<256, 256, 0, stream>>>(W1, W2, wm1, wm2);

  // stage 2 (edge: 1024 blocks, PPB=32 — round-0 proven)
  gemm_xt_k<<<dim3(NPTS / GBN, 256 / GBM, NB), dim3(16, 16), 0, stream>>>(
      x0b, 128, (long)NPTS * 128, wm1, 128, uv, 256, (long)NPTS * 256);
  edge_max_t<64, 32><<<dim3(NPTS / 32 * 2 * NB), 256, 0, stream>>>(uv, 256, 128, 128, idx,
                                                                   ym1, stats);
  finalize_scb_k<<<1, 256, 0, stream>>>(stats, scb1, 256, 1.0f / 131072.0f);
  // stage 3
  gemm_aff_k<<<dim3(NPTS / GBN, 512 / GBM, NB), dim3(16, 16), 0, stream>>>(
      ym1, scb1, wm2, uv, 512, (long)NPTS * 512);
  edge_max_t<128, 32><<<dim3(NPTS / 32 * 2 * NB), 256, 0, stream>>>(uv, 512, 256, 256, idx,
                                                                    ym2, stats + 512);
  finalize_scb_k<<<2, 256, 0, stream>>>(stats + 512, scb2, 512, 1.0f / 131072.0f);
  // stage 4: 128x64 tile, split-K 2-way -> (64, 4, 2) = 512 blocks = 2/CU.
  // kh0 -> y4, kh1 -> uv (dead after stage-3 edge); colstats2 sums halves.
  gemm_cat_k<<<dim3(NPTS / GBN, 4, NB), dim3(16, 16), 0, stream>>>(
      x0b, ym1, ym2, scb1, scb2, W3, y4, uv);
  colstats2_k<<<dim3(NPTS / 64, NB), 256, 0, stream>>>(y4, uv, stats + 1536);
  final_k<<<dim3(NPTS / 32, CH / 32, NB), dim3(32, 8), 0, stream>>>(y4, stats + 1536, out);
}